// Round 1
// baseline (4689.279 us; speedup 1.0000x reference)
//
#include <hip/hip_runtime.h>
#include <math.h>

#define ALPHA 0.2f

static __device__ __forceinline__ float lrelu(float v) {
    return v > 0.0f ? v : ALPHA * v;
}

constexpr int Nn = 100, Hn = 32;
constexpr int F1 = 96, F2 = 160, F3 = 192;

// One block per (b,i). Computes sum_j fe(concat(x_i, x_j, dist_ij)) -> hin[bi][0..191]
// and copies x_i -> hin[bi][192..223]. hin row stride = 256.
__global__ __launch_bounds__(256) void edge_kernel(
    const float* __restrict__ x,
    const float* __restrict__ w0, const float* __restrict__ b0,
    const float* __restrict__ w1, const float* __restrict__ b1,
    const float* __restrict__ w2, const float* __restrict__ b2,
    float* __restrict__ hin)
{
    __shared__ float xb[Nn][33];
    __shared__ float base0[F1];
    __shared__ float dist[Nn];
    __shared__ float H0s[Nn][97];
    __shared__ float H1s[Nn][161];

    const int bi = blockIdx.x;
    const int b = bi / Nn, i = bi % Nn;
    const int t = threadIdx.x;
    const int lane = t & 63, wave = t >> 6;

    const float* xbg = x + (size_t)b * Nn * Hn;
    for (int idx = t; idx < Nn * Hn; idx += 256)
        xb[idx >> 5][idx & 31] = xbg[idx];
    __syncthreads();

    float* hinrow = hin + (size_t)bi * 256;
    if (t < Hn) hinrow[192 + t] = xb[i][t];

    // base0[o] = b0[o] + dot(w0[o][0:32], x_i)   (x_i part uniform over j)
    if (t < F1) {
        const float* wr = w0 + (size_t)t * 65;
        float acc = b0[t];
        #pragma unroll
        for (int k = 0; k < Hn; ++k) acc += wr[k] * xb[i][k];
        base0[t] = acc;
    }
    if (t < Nn) {
        float dx = xb[t][0] - xb[i][0] + 1e-12f;
        float dy = xb[t][1] - xb[i][1] + 1e-12f;
        dist[t] = sqrtf(dx * dx + dy * dy);
    }
    __syncthreads();

    // ---- layer 1: H0[j][o] = lrelu(base0[o] + W0[o][32:64].x_j + W0[o][64]*d) ----
    for (int q = wave; q < F1 / 4; q += 4) {
        const int o = q * 4;
        const float* wr0 = w0 + (size_t)(o + 0) * 65 + 32;
        const float* wr1 = w0 + (size_t)(o + 1) * 65 + 32;
        const float* wr2 = w0 + (size_t)(o + 2) * 65 + 32;
        const float* wr3 = w0 + (size_t)(o + 3) * 65 + 32;
        for (int rep = 0; rep < 2; ++rep) {
            const int j = lane + 64 * rep;
            if (j < Nn) {
                const float d = dist[j];
                float a0 = base0[o + 0] + wr0[32] * d;
                float a1 = base0[o + 1] + wr1[32] * d;
                float a2 = base0[o + 2] + wr2[32] * d;
                float a3 = base0[o + 3] + wr3[32] * d;
                #pragma unroll 8
                for (int k = 0; k < Hn; ++k) {
                    const float h = xb[j][k];
                    a0 += wr0[k] * h; a1 += wr1[k] * h;
                    a2 += wr2[k] * h; a3 += wr3[k] * h;
                }
                H0s[j][o + 0] = lrelu(a0); H0s[j][o + 1] = lrelu(a1);
                H0s[j][o + 2] = lrelu(a2); H0s[j][o + 3] = lrelu(a3);
            }
        }
    }
    __syncthreads();

    // ---- layer 2: H1[j][o] = lrelu(b1[o] + W1[o].H0[j]) ----
    for (int q = wave; q < F2 / 4; q += 4) {
        const int o = q * 4;
        const float* wr = w1 + (size_t)o * F1;
        for (int rep = 0; rep < 2; ++rep) {
            const int j = lane + 64 * rep;
            if (j < Nn) {
                float a0 = b1[o], a1 = b1[o + 1], a2 = b1[o + 2], a3 = b1[o + 3];
                #pragma unroll 4
                for (int k = 0; k < F1; k += 4) {
                    const float4 v0 = *(const float4*)(wr + k);
                    const float4 v1 = *(const float4*)(wr + F1 + k);
                    const float4 v2 = *(const float4*)(wr + 2 * F1 + k);
                    const float4 v3 = *(const float4*)(wr + 3 * F1 + k);
                    const float h0 = H0s[j][k],     h1 = H0s[j][k + 1];
                    const float h2 = H0s[j][k + 2], h3 = H0s[j][k + 3];
                    a0 += v0.x * h0 + v0.y * h1 + v0.z * h2 + v0.w * h3;
                    a1 += v1.x * h0 + v1.y * h1 + v1.z * h2 + v1.w * h3;
                    a2 += v2.x * h0 + v2.y * h1 + v2.z * h2 + v2.w * h3;
                    a3 += v3.x * h0 + v3.y * h1 + v3.z * h2 + v3.w * h3;
                }
                H1s[j][o + 0] = lrelu(a0); H1s[j][o + 1] = lrelu(a1);
                H1s[j][o + 2] = lrelu(a2); H1s[j][o + 3] = lrelu(a3);
            }
        }
    }
    __syncthreads();

    // ---- layer 3 + sum over j ----
    for (int q = wave; q < F3 / 4; q += 4) {
        const int o = q * 4;
        const float* wr = w2 + (size_t)o * F2;
        float s0 = 0.f, s1 = 0.f, s2 = 0.f, s3 = 0.f;
        for (int rep = 0; rep < 2; ++rep) {
            const int j = lane + 64 * rep;
            if (j < Nn) {
                float a0 = b2[o], a1 = b2[o + 1], a2 = b2[o + 2], a3 = b2[o + 3];
                #pragma unroll 4
                for (int k = 0; k < F2; k += 4) {
                    const float4 v0 = *(const float4*)(wr + k);
                    const float4 v1 = *(const float4*)(wr + F2 + k);
                    const float4 v2 = *(const float4*)(wr + 2 * F2 + k);
                    const float4 v3 = *(const float4*)(wr + 3 * F2 + k);
                    const float h0 = H1s[j][k],     h1 = H1s[j][k + 1];
                    const float h2 = H1s[j][k + 2], h3 = H1s[j][k + 3];
                    a0 += v0.x * h0 + v0.y * h1 + v0.z * h2 + v0.w * h3;
                    a1 += v1.x * h0 + v1.y * h1 + v1.z * h2 + v1.w * h3;
                    a2 += v2.x * h0 + v2.y * h1 + v2.z * h2 + v2.w * h3;
                    a3 += v3.x * h0 + v3.y * h1 + v3.z * h2 + v3.w * h3;
                }
                s0 += lrelu(a0); s1 += lrelu(a1); s2 += lrelu(a2); s3 += lrelu(a3);
            }
        }
        #pragma unroll
        for (int off = 32; off > 0; off >>= 1) {
            s0 += __shfl_down(s0, off);
            s1 += __shfl_down(s1, off);
            s2 += __shfl_down(s2, off);
            s3 += __shfl_down(s3, off);
        }
        if (lane == 0) {
            hinrow[o + 0] = s0; hinrow[o + 1] = s1;
            hinrow[o + 2] = s2; hinrow[o + 3] = s3;
        }
    }
}

// Generic row-MLP: out[r][o] = act(bias[o] + W[o].in[r])
// 64 rows per block; lanes = rows; o-quad uniform per wave.
__global__ __launch_bounds__(256) void mlp_kernel(
    const float* __restrict__ in, const float* __restrict__ w,
    const float* __restrict__ bias, float* __restrict__ out,
    int K, int in_stride, int O, int act)  // act 0: lrelu, 1: tanh
{
    __shared__ float hin[64][257];
    const int r0 = blockIdx.x * 64;
    const int t = threadIdx.x, lane = t & 63, wave = t >> 6;

    for (int idx = t; idx < 64 * K; idx += 256) {
        const int r = idx / K, k = idx - r * K;
        hin[r][k] = in[(size_t)(r0 + r) * in_stride + k];
    }
    __syncthreads();

    for (int q = wave; q * 4 < O; q += 4) {
        const int o = q * 4;
        if (o + 4 <= O) {
            const float* wr = w + (size_t)o * K;
            float a0 = bias[o], a1 = bias[o + 1], a2 = bias[o + 2], a3 = bias[o + 3];
            #pragma unroll 4
            for (int k = 0; k < K; k += 4) {
                const float4 v0 = *(const float4*)(wr + k);
                const float4 v1 = *(const float4*)(wr + K + k);
                const float4 v2 = *(const float4*)(wr + 2 * K + k);
                const float4 v3 = *(const float4*)(wr + 3 * K + k);
                const float h0 = hin[lane][k],     h1 = hin[lane][k + 1];
                const float h2 = hin[lane][k + 2], h3 = hin[lane][k + 3];
                a0 += v0.x * h0 + v0.y * h1 + v0.z * h2 + v0.w * h3;
                a1 += v1.x * h0 + v1.y * h1 + v1.z * h2 + v1.w * h3;
                a2 += v2.x * h0 + v2.y * h1 + v2.z * h2 + v2.w * h3;
                a3 += v3.x * h0 + v3.y * h1 + v3.z * h2 + v3.w * h3;
            }
            const size_t ob = (size_t)(r0 + lane) * O + o;
            if (act == 0) {
                out[ob + 0] = lrelu(a0); out[ob + 1] = lrelu(a1);
                out[ob + 2] = lrelu(a2); out[ob + 3] = lrelu(a3);
            } else {
                out[ob + 0] = tanhf(a0); out[ob + 1] = tanhf(a1);
                out[ob + 2] = tanhf(a2); out[ob + 3] = tanhf(a3);
            }
        } else {
            for (int u = 0; u < O - o; ++u) {
                const float* wr = w + (size_t)(o + u) * K;
                float a = bias[o + u];
                for (int k = 0; k < K; ++k) a += wr[k] * hin[lane][k];
                a = (act == 0) ? lrelu(a) : tanhf(a);
                out[(size_t)(r0 + lane) * O + o + u] = a;
            }
        }
    }
}

extern "C" void kernel_launch(void* const* d_in, const int* in_sizes, int n_in,
                              void* d_out, int out_size, void* d_ws, size_t ws_size,
                              hipStream_t stream) {
    (void)in_sizes; (void)n_in; (void)out_size; (void)ws_size;
    const float* x     = (const float*)d_in[0];
    const float* fe_w0 = (const float*)d_in[1];
    const float* fe_b0 = (const float*)d_in[2];
    const float* fe_w1 = (const float*)d_in[3];
    const float* fe_b1 = (const float*)d_in[4];
    const float* fe_w2 = (const float*)d_in[5];
    const float* fe_b2 = (const float*)d_in[6];
    const float* fn_w0 = (const float*)d_in[7];
    const float* fn_b0 = (const float*)d_in[8];
    const float* fn_w1 = (const float*)d_in[9];
    const float* fn_b1 = (const float*)d_in[10];
    const float* fn_w2 = (const float*)d_in[11];
    const float* fn_b2 = (const float*)d_in[12];
    float* out  = (float*)d_out;
    float* buf0 = (float*)d_ws;                 // [6400][256]
    float* buf1 = buf0 + (size_t)6400 * 256;    // [6400][256]

    edge_kernel<<<6400, 256, 0, stream>>>(x, fe_w0, fe_b0, fe_w1, fe_b1,
                                          fe_w2, fe_b2, buf0);
    mlp_kernel<<<100, 256, 0, stream>>>(buf0, fn_w0, fn_b0, buf1, 224, 256, 256, 0);
    mlp_kernel<<<100, 256, 0, stream>>>(buf1, fn_w1, fn_b1, buf0, 256, 256, 256, 0);
    mlp_kernel<<<100, 256, 0, stream>>>(buf0, fn_w2, fn_b2, out, 256, 256, 3, 1);
}

// Round 2
// 486.886 us; speedup vs baseline: 9.6312x; 9.6312x over previous
//
#include <hip/hip_runtime.h>
#include <hip/hip_bf16.h>
#include <math.h>

#define ALPHA 0.2f

typedef __attribute__((ext_vector_type(8))) short bf16x8;
typedef __attribute__((ext_vector_type(4))) float f32x4;

static __device__ __forceinline__ float lrelu(float v) {
    return v > 0.0f ? v : ALPHA * v;
}

// fp32 -> bf16 round-to-nearest-even
static __device__ __forceinline__ uint16_t f2b(float f) {
    union { float f; uint32_t u; } c; c.f = f;
    const uint32_t u = c.u + 0x7FFFu + ((c.u >> 16) & 1u);
    return (uint16_t)(u >> 16);
}

// ---------------- weight conversion: fp32 -> bf16 (+ layer-1 repack) -------
// wb0p[96][64]: cols 0..31 = W0[:,32:64] (x_j half), col 32 = W0[:,64] (dist),
// cols 33..63 = 0.   wb1[160][96], wb2[192][160]: straight bf16 casts.
__global__ __launch_bounds__(256) void convert_weights(
    const float* __restrict__ w0, const float* __restrict__ w1,
    const float* __restrict__ w2,
    uint16_t* __restrict__ o0, uint16_t* __restrict__ o1,
    uint16_t* __restrict__ o2)
{
    const int t0 = blockIdx.x * 256 + threadIdx.x;
    const int stride = gridDim.x * 256;
    for (int t = t0; t < 96 * 64; t += stride) {
        const int n = t >> 6, k = t & 63;
        o0[t] = f2b(k < 33 ? w0[n * 65 + 32 + k] : 0.0f);
    }
    for (int t = t0; t < 160 * 96; t += stride) o1[t] = f2b(w1[t]);
    for (int t = t0; t < 192 * 160; t += stride) o2[t] = f2b(w2[t]);
}

// ---------------- MFMA layer: D[112][NT*16] = lrelu(Hin * W^T + bias) ------
// A-frag: lane reads Hin[m*16 + (lane&15)][kt*32 + 8*(lane>>4) .. +7]
// B-frag: lane reads W[n0 + (lane&15)][kt*32 + 8*(lane>>4) .. +7]  (row-major W)
// C/D:    lane holds D[m*16 + 4*(lane>>4) + r][n0 + (lane&15)]  (verified m89)
// MODE 0: lrelu -> bf16 -> Hout LDS.  MODE 1: lrelu, mask rows>=100, sum rows,
//         cross-group shfl reduce, write fp32 sums to sumout.
template<int KT, int MODE>
static __device__ __forceinline__ void mfma_layer(
    const uint16_t* __restrict__ Hin, const int hstride,
    const uint16_t* __restrict__ W, const int wK,
    const float* __restrict__ bias,
    uint16_t* __restrict__ Hout, const int ostride,
    float* __restrict__ sumout,
    const int NT, const int lane, const int wave)
{
    const int col = lane & 15, g = lane >> 4;
    f32x4 acc[3][7];
    int ntg[3];
    bool real[3];
#pragma unroll
    for (int s = 0; s < 3; ++s) {
        const int nt = wave + 4 * s;
        real[s] = (nt < NT);
        ntg[s] = real[s] ? nt : (NT - 1);
    }
#pragma unroll
    for (int s = 0; s < 3; ++s) {
        const float bv = bias[ntg[s] * 16 + col];
#pragma unroll
        for (int m = 0; m < 7; ++m) acc[s][m] = (f32x4){bv, bv, bv, bv};
    }
#pragma unroll
    for (int kt = 0; kt < KT; ++kt) {
        const int kofs = kt * 32 + 8 * g;
        bf16x8 bf[3];
#pragma unroll
        for (int s = 0; s < 3; ++s)
            bf[s] = *(const bf16x8*)(W + (size_t)(ntg[s] * 16 + col) * wK + kofs);
#pragma unroll
        for (int m = 0; m < 7; ++m) {
            const bf16x8 af = *(const bf16x8*)(Hin + (m * 16 + col) * hstride + kofs);
#pragma unroll
            for (int s = 0; s < 3; ++s)
                acc[s][m] = __builtin_amdgcn_mfma_f32_16x16x32_bf16(
                    af, bf[s], acc[s][m], 0, 0, 0);
        }
    }
    if (MODE == 0) {
#pragma unroll
        for (int s = 0; s < 3; ++s) {
            if (!real[s]) continue;
            const int n0 = ntg[s] * 16;
#pragma unroll
            for (int m = 0; m < 7; ++m) {
#pragma unroll
                for (int r = 0; r < 4; ++r) {
                    const int row = m * 16 + 4 * g + r;
                    Hout[row * ostride + n0 + col] = f2b(lrelu(acc[s][m][r]));
                }
            }
        }
    } else {
#pragma unroll
        for (int s = 0; s < 3; ++s) {
            float sum = 0.0f;
#pragma unroll
            for (int m = 0; m < 7; ++m) {
#pragma unroll
                for (int r = 0; r < 4; ++r) {
                    const int row = m * 16 + 4 * g + r;
                    if (row < 100) sum += lrelu(acc[s][m][r]);
                }
            }
            sum += __shfl_xor(sum, 16);
            sum += __shfl_xor(sum, 32);
            if (real[s] && lane < 16) sumout[ntg[s] * 16 + col] = sum;
        }
    }
}

// ---------------- edge kernel: one block per (b,i) -------------------------
// LDS regions (unioned): R1 = A1[112][72] then H2[112][168];
//                        R2 = xb[100][33] (f32) then H1[112][104].
// Odd 16B-unit row strides (9/13/21) -> <=2-way bank aliasing on ds_read_b128.
__global__ __launch_bounds__(256) void edge_kernel(
    const float* __restrict__ x,
    const float* __restrict__ w0f, const float* __restrict__ b0f,
    const float* __restrict__ b1f, const float* __restrict__ b2f,
    const uint16_t* __restrict__ wb0p, const uint16_t* __restrict__ wb1,
    const uint16_t* __restrict__ wb2,
    float* __restrict__ hin)
{
    __shared__ __align__(16) uint16_t R1[112 * 168];   // 37632 B
    __shared__ __align__(16) uint16_t R2[112 * 104];   // 23296 B
    __shared__ float base0[96];
    __shared__ float dist[112];

    const int bi = blockIdx.x;
    const int b = bi / 100, i = bi % 100;
    const int t = threadIdx.x;
    const int lane = t & 63, wave = t >> 6;

    float* xb = (float*)R2;  // [100][33]
    const float* xg = x + (size_t)b * 3200;
    for (int idx = t; idx < 3200; idx += 256)
        xb[(idx >> 5) * 33 + (idx & 31)] = xg[idx];
    __syncthreads();

    float* hinrow = hin + (size_t)bi * 256;
    if (t < 32) hinrow[192 + t] = xb[i * 33 + t];      // node input tail = x_i
    if (t < 96) {                                      // base0 = b0 + W0[:, :32].x_i (fp32)
        const float* wr = w0f + t * 65;
        float a = b0f[t];
#pragma unroll
        for (int k = 0; k < 32; ++k) a += wr[k] * xb[i * 33 + k];
        base0[t] = a;
    }
    if (t < 100) {
        const float dx = xb[t * 33 + 0] - xb[i * 33 + 0] + 1e-12f;
        const float dy = xb[t * 33 + 1] - xb[i * 33 + 1] + 1e-12f;
        dist[t] = sqrtf(dx * dx + dy * dy);
    }
    __syncthreads();

    // Build A1 (bf16): row j = [x_j(32), d_j, 0..0]; rows 100..111 zero.
    for (int idx = t; idx < 112 * 64; idx += 256) {
        const int r = idx >> 6, k = idx & 63;
        float v = 0.0f;
        if (r < 100) v = (k < 32) ? xb[r * 33 + k] : (k == 32 ? dist[r] : 0.0f);
        R1[r * 72 + k] = f2b(v);
    }
    __syncthreads();

    mfma_layer<2, 0>(R1, 72, wb0p, 64, base0, R2, 104, nullptr, 6, lane, wave);
    __syncthreads();
    mfma_layer<3, 0>(R2, 104, wb1, 96, b1f, R1, 168, nullptr, 10, lane, wave);
    __syncthreads();
    mfma_layer<5, 1>(R1, 168, wb2, 160, b2f, nullptr, 0, hinrow, 12, lane, wave);
}

// ---------------- node MLP (fp32, unchanged from round 1) ------------------
__global__ __launch_bounds__(256) void mlp_kernel(
    const float* __restrict__ in, const float* __restrict__ w,
    const float* __restrict__ bias, float* __restrict__ out,
    int K, int in_stride, int O, int act)  // act 0: lrelu, 1: tanh
{
    __shared__ float hin[64][257];
    const int r0 = blockIdx.x * 64;
    const int t = threadIdx.x, lane = t & 63, wave = t >> 6;

    for (int idx = t; idx < 64 * K; idx += 256) {
        const int r = idx / K, k = idx - r * K;
        hin[r][k] = in[(size_t)(r0 + r) * in_stride + k];
    }
    __syncthreads();

    for (int q = wave; q * 4 < O; q += 4) {
        const int o = q * 4;
        if (o + 4 <= O) {
            const float* wr = w + (size_t)o * K;
            float a0 = bias[o], a1 = bias[o + 1], a2 = bias[o + 2], a3 = bias[o + 3];
#pragma unroll 4
            for (int k = 0; k < K; k += 4) {
                const float4 v0 = *(const float4*)(wr + k);
                const float4 v1 = *(const float4*)(wr + K + k);
                const float4 v2 = *(const float4*)(wr + 2 * K + k);
                const float4 v3 = *(const float4*)(wr + 3 * K + k);
                const float h0 = hin[lane][k],     h1 = hin[lane][k + 1];
                const float h2 = hin[lane][k + 2], h3 = hin[lane][k + 3];
                a0 += v0.x * h0 + v0.y * h1 + v0.z * h2 + v0.w * h3;
                a1 += v1.x * h0 + v1.y * h1 + v1.z * h2 + v1.w * h3;
                a2 += v2.x * h0 + v2.y * h1 + v2.z * h2 + v2.w * h3;
                a3 += v3.x * h0 + v3.y * h1 + v3.z * h2 + v3.w * h3;
            }
            const size_t ob = (size_t)(r0 + lane) * O + o;
            if (act == 0) {
                out[ob + 0] = lrelu(a0); out[ob + 1] = lrelu(a1);
                out[ob + 2] = lrelu(a2); out[ob + 3] = lrelu(a3);
            } else {
                out[ob + 0] = tanhf(a0); out[ob + 1] = tanhf(a1);
                out[ob + 2] = tanhf(a2); out[ob + 3] = tanhf(a3);
            }
        } else {
            for (int u = 0; u < O - o; ++u) {
                const float* wr = w + (size_t)(o + u) * K;
                float a = bias[o + u];
                for (int k = 0; k < K; ++k) a += wr[k] * hin[lane][k];
                a = (act == 0) ? lrelu(a) : tanhf(a);
                out[(size_t)(r0 + lane) * O + o + u] = a;
            }
        }
    }
}

extern "C" void kernel_launch(void* const* d_in, const int* in_sizes, int n_in,
                              void* d_out, int out_size, void* d_ws, size_t ws_size,
                              hipStream_t stream) {
    (void)in_sizes; (void)n_in; (void)out_size; (void)ws_size;
    const float* x     = (const float*)d_in[0];
    const float* fe_w0 = (const float*)d_in[1];
    const float* fe_b0 = (const float*)d_in[2];
    const float* fe_w1 = (const float*)d_in[3];
    const float* fe_b1 = (const float*)d_in[4];
    const float* fe_w2 = (const float*)d_in[5];
    const float* fe_b2 = (const float*)d_in[6];
    const float* fn_w0 = (const float*)d_in[7];
    const float* fn_b0 = (const float*)d_in[8];
    const float* fn_w1 = (const float*)d_in[9];
    const float* fn_b1 = (const float*)d_in[10];
    const float* fn_w2 = (const float*)d_in[11];
    const float* fn_b2 = (const float*)d_in[12];
    float* out  = (float*)d_out;

    float* buf0 = (float*)d_ws;                 // [6400][256] node-MLP input
    float* buf1 = buf0 + (size_t)6400 * 256;    // [6400][256] ping-pong
    // bf16 weights live in buf1's space: edge_kernel reads them, and buf1 is
    // only written by mlp_kernel AFTER edge_kernel completes (stream order).
    uint16_t* wb0p = (uint16_t*)buf1;           // 96*64
    uint16_t* wb1  = wb0p + 96 * 64;            // 160*96
    uint16_t* wb2  = wb1 + 160 * 96;            // 192*160

    convert_weights<<<64, 256, 0, stream>>>(fe_w0, fe_w1, fe_w2, wb0p, wb1, wb2);
    edge_kernel<<<6400, 256, 0, stream>>>(x, fe_w0, fe_b0, fe_b1, fe_b2,
                                          wb0p, wb1, wb2, buf0);
    mlp_kernel<<<100, 256, 0, stream>>>(buf0, fn_w0, fn_b0, buf1, 224, 256, 256, 0);
    mlp_kernel<<<100, 256, 0, stream>>>(buf1, fn_w1, fn_b1, buf0, 256, 256, 256, 0);
    mlp_kernel<<<100, 256, 0, stream>>>(buf0, fn_w2, fn_b2, out, 256, 256, 3, 1);
}

// Round 3
// 166.317 us; speedup vs baseline: 28.1948x; 2.9275x over previous
//
#include <hip/hip_runtime.h>
#include <hip/hip_bf16.h>
#include <math.h>

#define ALPHA 0.2f

typedef __attribute__((ext_vector_type(8))) short bf16x8;
typedef __attribute__((ext_vector_type(4))) float f32x4;

static __device__ __forceinline__ float lrelu(float v) {
    return v > 0.0f ? v : ALPHA * v;
}
// fp32 -> bf16 round-to-nearest-even
static __device__ __forceinline__ uint16_t f2b(float f) {
    union { float f; uint32_t u; } c; c.f = f;
    const uint32_t u = c.u + 0x7FFFu + ((c.u >> 16) & 1u);
    return (uint16_t)(u >> 16);
}
static __device__ __forceinline__ float b2f16(uint16_t h) {
    union { uint32_t u; float f; } c; c.u = ((uint32_t)h) << 16; return c.f;
}

// ---------------- weight conversion (once per call) ------------------------
// o0[96][32] = W0[:,32:64] (x_j half), od[96] = W0[:,64] (dist col, fp32),
// o1[160][96], o2[192][160], of0[256][224], of1[256][256]: bf16 casts.
__global__ __launch_bounds__(256) void convert_weights(
    const float* __restrict__ w0, const float* __restrict__ w1,
    const float* __restrict__ w2, const float* __restrict__ f0,
    const float* __restrict__ f1,
    uint16_t* __restrict__ o0, float* __restrict__ od,
    uint16_t* __restrict__ o1, uint16_t* __restrict__ o2,
    uint16_t* __restrict__ of0, uint16_t* __restrict__ of1)
{
    const int t0 = blockIdx.x * 256 + threadIdx.x;
    const int stride = gridDim.x * 256;
    for (int t = t0; t < 96 * 32; t += stride) {
        const int n = t >> 5, k = t & 31;
        o0[t] = f2b(w0[n * 65 + 32 + k]);
    }
    for (int t = t0; t < 96; t += stride) od[t] = w0[t * 65 + 64];
    for (int t = t0; t < 160 * 96; t += stride) o1[t] = f2b(w1[t]);
    for (int t = t0; t < 192 * 160; t += stride) o2[t] = f2b(w2[t]);
    for (int t = t0; t < 256 * 224; t += stride) of0[t] = f2b(f0[t]);
    for (int t = t0; t < 256 * 256; t += stride) of1[t] = f2b(f1[t]);
}

// ---------------- edge kernel: one block per (b,i) -------------------------
// LDS: R1 = union{ A1[112][32] s40, H2local[64][160] s168 }  (21504 B)
//      R2 = union{ xb f32[100][33], H1[112][96] s104 }        (23296 B)
// All bf16 row strides are odd multiples of 8 elems -> 2-way (free) on b128.
__global__ __launch_bounds__(256, 3) void edge_kernel(
    const float* __restrict__ x,
    const float* __restrict__ w0f, const float* __restrict__ b0f,
    const float* __restrict__ b1f, const float* __restrict__ eb2,
    const uint16_t* __restrict__ wb0p, const float* __restrict__ wd0,
    const uint16_t* __restrict__ wb1, const uint16_t* __restrict__ wb2,
    float* __restrict__ hin)
{
    __shared__ __align__(16) uint16_t R1[64 * 168];
    __shared__ __align__(16) uint16_t R2[112 * 104];
    __shared__ __align__(16) float base0[96];
    __shared__ __align__(16) float dist[112];

    const int bi = blockIdx.x;
    const int b = bi / 100, i = bi % 100;
    const int t = threadIdx.x;
    const int lane = t & 63, wave = t >> 6;
    const int col = lane & 15, g = lane >> 4;

    float* xb = (float*)R2;  // [100][33] fp32
    const float* xg = x + (size_t)b * 3200;
    for (int idx = t; idx < 3200; idx += 256)
        xb[(idx >> 5) * 33 + (idx & 31)] = xg[idx];
    __syncthreads();

    float* hinrow = hin + (size_t)bi * 256;
    if (t < 32) hinrow[192 + t] = xb[i * 33 + t];   // node-input tail = x_i
    if (t < 96) {                                   // base0 = b0 + W0[:,:32].x_i
        const float* wr = w0f + t * 65;
        float a = b0f[t];
#pragma unroll
        for (int k = 0; k < 32; ++k) a += wr[k] * xb[i * 33 + k];
        base0[t] = a;
    }
    if (t < 112) {
        float d = 0.0f;
        if (t < 100) {
            const float dx = xb[t * 33 + 0] - xb[i * 33 + 0] + 1e-12f;
            const float dy = xb[t * 33 + 1] - xb[i * 33 + 1] + 1e-12f;
            d = sqrtf(dx * dx + dy * dy);
        }
        dist[t] = d;
    }
    // A1[112][32] (stride 40): row j = x_j, rows >=100 zero
    for (int idx = t; idx < 112 * 32; idx += 256) {
        const int r = idx >> 5, k = idx & 31;
        R1[r * 40 + k] = f2b(r < 100 ? xb[r * 33 + k] : 0.0f);
    }
    __syncthreads();

    // ---- L1: H1[112][96] = lrelu(A1(K=32) @ W0x^T + wd0*dist + base0) ----
    {
        f32x4 acc[2][7];
#pragma unroll
        for (int s = 0; s < 2; ++s) {
            const int nt = wave + 4 * s;
            if (nt < 6) {
                const float bv = base0[nt * 16 + col];
                const float wdv = wd0[nt * 16 + col];
                const bf16x8 bfr = *(const bf16x8*)(wb0p + (nt * 16 + col) * 32 + 8 * g);
#pragma unroll
                for (int m = 0; m < 7; ++m) {
                    acc[s][m] = (f32x4){bv, bv, bv, bv};
                    const bf16x8 af = *(const bf16x8*)(R1 + (m * 16 + col) * 40 + 8 * g);
                    acc[s][m] = __builtin_amdgcn_mfma_f32_16x16x32_bf16(af, bfr, acc[s][m], 0, 0, 0);
                    const f32x4 dq = *(const f32x4*)(dist + m * 16 + 4 * g);
#pragma unroll
                    for (int r = 0; r < 4; ++r) acc[s][m][r] += wdv * dq[r];
                }
            }
        }
        // epilogue writes H1 over xb (xb dead: all reads happened pre-barrier)
#pragma unroll
        for (int s = 0; s < 2; ++s) {
            const int nt = wave + 4 * s;
            if (nt < 6) {
#pragma unroll
                for (int m = 0; m < 7; ++m)
#pragma unroll
                    for (int r = 0; r < 4; ++r)
                        R2[(m * 16 + 4 * g + r) * 104 + nt * 16 + col] =
                            f2b(lrelu(acc[s][m][r]));
            }
        }
    }
    __syncthreads();

    // ---- L2 -> L3 in two m-subsets sharing H2local[64][160] (stride 168) ---
    float ssum[3] = {0.f, 0.f, 0.f};
#pragma unroll
    for (int sub = 0; sub < 2; ++sub) {
        const int MT = (sub == 0) ? 4 : 3;
        {   // L2: H2local = lrelu(H1[sub rows] @ W1^T + b1)
            f32x4 acc[3][4];
#pragma unroll
            for (int s = 0; s < 3; ++s) {
                const int nt = wave + 4 * s;
                if (nt < 10) {
                    const float bv = b1f[nt * 16 + col];
#pragma unroll
                    for (int m = 0; m < 4; ++m) if (m < MT)
                        acc[s][m] = (f32x4){bv, bv, bv, bv};
#pragma unroll
                    for (int kt = 0; kt < 3; ++kt) {
                        const bf16x8 bfr = *(const bf16x8*)(
                            wb1 + (size_t)(nt * 16 + col) * 96 + kt * 32 + 8 * g);
#pragma unroll
                        for (int m = 0; m < 4; ++m) if (m < MT) {
                            const bf16x8 af = *(const bf16x8*)(
                                R2 + ((sub * 4 + m) * 16 + col) * 104 + kt * 32 + 8 * g);
                            acc[s][m] = __builtin_amdgcn_mfma_f32_16x16x32_bf16(
                                af, bfr, acc[s][m], 0, 0, 0);
                        }
                    }
#pragma unroll
                    for (int m = 0; m < 4; ++m) if (m < MT)
#pragma unroll
                        for (int r = 0; r < 4; ++r)
                            R1[(m * 16 + 4 * g + r) * 168 + nt * 16 + col] =
                                f2b(lrelu(acc[s][m][r]));
                }
            }
        }
        __syncthreads();
        {   // L3 partial: accumulate lrelu(H2local @ W2^T + b2) row-sums
            f32x4 acc[3][4];
#pragma unroll
            for (int s = 0; s < 3; ++s) {
                const int nt = wave + 4 * s;   // NT=12: always real
                const float bv = eb2[nt * 16 + col];
#pragma unroll
                for (int m = 0; m < 4; ++m) if (m < MT)
                    acc[s][m] = (f32x4){bv, bv, bv, bv};
#pragma unroll
                for (int kt = 0; kt < 5; ++kt) {
                    const bf16x8 bfr = *(const bf16x8*)(
                        wb2 + (size_t)(nt * 16 + col) * 160 + kt * 32 + 8 * g);
#pragma unroll
                    for (int m = 0; m < 4; ++m) if (m < MT) {
                        const bf16x8 af = *(const bf16x8*)(
                            R1 + (m * 16 + col) * 168 + kt * 32 + 8 * g);
                        acc[s][m] = __builtin_amdgcn_mfma_f32_16x16x32_bf16(
                            af, bfr, acc[s][m], 0, 0, 0);
                    }
                }
                float ps = 0.0f;
#pragma unroll
                for (int m = 0; m < 4; ++m) if (m < MT) {
                    const bool needmask = (sub == 1 && m == 2);  // rows 96..111
                    const int rowbase = sub * 64 + m * 16 + 4 * g;
#pragma unroll
                    for (int r = 0; r < 4; ++r) {
                        if (!needmask || (rowbase + r < 100))
                            ps += lrelu(acc[s][m][r]);
                    }
                }
                ssum[s] += ps;
            }
        }
        if (sub == 0) __syncthreads();   // H2local consumed before overwrite
    }
#pragma unroll
    for (int s = 0; s < 3; ++s) {
        float v = ssum[s];
        v += __shfl_xor(v, 16);
        v += __shfl_xor(v, 32);
        if (lane < 16) hinrow[(wave + 4 * s) * 16 + col] = v;
    }
}

// ---------------- fused node MLP: 16 rows per block, 400 blocks ------------
// L0: 224->256 (MFMA bf16), L1: 256->256 (MFMA bf16), L2: 256->3 fp32 + tanh.
__global__ __launch_bounds__(256) void node_kernel(
    const float* __restrict__ hin,
    const uint16_t* __restrict__ wfn0, const float* __restrict__ fb0,
    const uint16_t* __restrict__ wfn1, const float* __restrict__ fb1,
    const float* __restrict__ fw2, const float* __restrict__ fb2,
    float* __restrict__ out)
{
    __shared__ __align__(16) uint16_t RA[16 * 264];  // union{Ain s232, H2 s264}
    __shared__ __align__(16) uint16_t RH[16 * 264];  // H (L0 out), s264
    const int t = threadIdx.x, lane = t & 63, wave = t >> 6;
    const int col = lane & 15, g = lane >> 4;
    const int r0 = blockIdx.x * 16;

    for (int r = wave; r < 16; r += 4) {
        const float* src = hin + (size_t)(r0 + r) * 256;
        for (int c = lane; c < 224; c += 64)
            RA[r * 232 + c] = f2b(src[c]);
    }
    __syncthreads();

    {   // L0: K=224 (kt 0..6), O=256 (16 nt; nt = wave + 4s)
        f32x4 acc[4];
#pragma unroll
        for (int s = 0; s < 4; ++s) {
            const float bv = fb0[(wave + 4 * s) * 16 + col];
            acc[s] = (f32x4){bv, bv, bv, bv};
        }
#pragma unroll
        for (int kt = 0; kt < 7; ++kt) {
            const bf16x8 af = *(const bf16x8*)(RA + col * 232 + kt * 32 + 8 * g);
#pragma unroll
            for (int s = 0; s < 4; ++s) {
                const int nt = wave + 4 * s;
                const bf16x8 bfr = *(const bf16x8*)(
                    wfn0 + (size_t)(nt * 16 + col) * 224 + kt * 32 + 8 * g);
                acc[s] = __builtin_amdgcn_mfma_f32_16x16x32_bf16(af, bfr, acc[s], 0, 0, 0);
            }
        }
#pragma unroll
        for (int s = 0; s < 4; ++s) {
            const int nt = wave + 4 * s;
#pragma unroll
            for (int r = 0; r < 4; ++r)
                RH[(4 * g + r) * 264 + nt * 16 + col] = f2b(lrelu(acc[s][r]));
        }
    }
    __syncthreads();
    {   // L1: K=256 (kt 0..7), in RH, out RA (Ain dead)
        f32x4 acc[4];
#pragma unroll
        for (int s = 0; s < 4; ++s) {
            const float bv = fb1[(wave + 4 * s) * 16 + col];
            acc[s] = (f32x4){bv, bv, bv, bv};
        }
#pragma unroll
        for (int kt = 0; kt < 8; ++kt) {
            const bf16x8 af = *(const bf16x8*)(RH + col * 264 + kt * 32 + 8 * g);
#pragma unroll
            for (int s = 0; s < 4; ++s) {
                const int nt = wave + 4 * s;
                const bf16x8 bfr = *(const bf16x8*)(
                    wfn1 + (size_t)(nt * 16 + col) * 256 + kt * 32 + 8 * g);
                acc[s] = __builtin_amdgcn_mfma_f32_16x16x32_bf16(af, bfr, acc[s], 0, 0, 0);
            }
        }
        __syncthreads();   // RA still being read as Ain? no - Ain dead; but H2 write must not race L0's... (all waves past L1 reads of RH by next barrier)
#pragma unroll
        for (int s = 0; s < 4; ++s) {
            const int nt = wave + 4 * s;
#pragma unroll
            for (int r = 0; r < 4; ++r)
                RA[(4 * g + r) * 264 + nt * 16 + col] = f2b(lrelu(acc[s][r]));
        }
    }
    __syncthreads();
    // L2 final: 3 outputs, fp32, + tanh.  t -> (row, o, ksub)
    const int row = t >> 4, u = t & 15;
    float h = 0.0f;
    if (u < 12) {
        const int o = u >> 2, ks = u & 3;
        const float* w = fw2 + o * 256 + ks * 64;
        const uint16_t* hr = RA + row * 264 + ks * 64;
        float a = 0.0f;
#pragma unroll 8
        for (int k = 0; k < 64; k += 4) {
            const ushort4 hv = *(const ushort4*)(hr + k);
            a += w[k + 0] * b2f16(hv.x) + w[k + 1] * b2f16(hv.y)
               + w[k + 2] * b2f16(hv.z) + w[k + 3] * b2f16(hv.w);
        }
        h = a;
    }
    h += __shfl_xor(h, 1);
    h += __shfl_xor(h, 2);
    if (u < 12 && (u & 3) == 0) {
        const int o = u >> 2;
        out[(size_t)(r0 + row) * 3 + o] = tanhf(h + fb2[o]);
    }
}

extern "C" void kernel_launch(void* const* d_in, const int* in_sizes, int n_in,
                              void* d_out, int out_size, void* d_ws, size_t ws_size,
                              hipStream_t stream) {
    (void)in_sizes; (void)n_in; (void)out_size; (void)ws_size;
    const float* x     = (const float*)d_in[0];
    const float* fe_w0 = (const float*)d_in[1];
    const float* fe_b0 = (const float*)d_in[2];
    const float* fe_w1 = (const float*)d_in[3];
    const float* fe_b1 = (const float*)d_in[4];
    const float* fe_w2 = (const float*)d_in[5];
    const float* fe_b2 = (const float*)d_in[6];
    const float* fn_w0 = (const float*)d_in[7];
    const float* fn_b0 = (const float*)d_in[8];
    const float* fn_w1 = (const float*)d_in[9];
    const float* fn_b1 = (const float*)d_in[10];
    const float* fn_w2 = (const float*)d_in[11];
    const float* fn_b2 = (const float*)d_in[12];
    float* out = (float*)d_out;

    float* buf0 = (float*)d_ws;                       // hin [6400][256] f32
    uint16_t* wq   = (uint16_t*)(buf0 + (size_t)6400 * 256);
    uint16_t* wb0p = wq;                              // 96*32
    uint16_t* wb1  = wb0p + 96 * 32;                  // 160*96
    uint16_t* wb2  = wb1 + 160 * 96;                  // 192*160
    uint16_t* wfn0 = wb2 + 192 * 160;                 // 256*224
    uint16_t* wfn1 = wfn0 + 256 * 224;                // 256*256
    float*    wd0  = (float*)(wfn1 + 256 * 256);      // 96 f32

    convert_weights<<<64, 256, 0, stream>>>(fe_w0, fe_w1, fe_w2, fn_w0, fn_w1,
                                            wb0p, wd0, wb1, wb2, wfn0, wfn1);
    edge_kernel<<<6400, 256, 0, stream>>>(x, fe_w0, fe_b0, fe_b1, fe_b2,
                                          wb0p, wd0, wb1, wb2, buf0);
    node_kernel<<<400, 256, 0, stream>>>(buf0, wfn0, fn_b0, wfn1, fn_b1,
                                         fn_w2, fn_b2, out);
}